// Round 7
// baseline (166.226 us; speedup 1.0000x reference)
//
#include <hip/hip_runtime.h>
#include <hip/hip_bf16.h>

typedef __bf16 bf16_t;
typedef __bf16 bf16x4 __attribute__((ext_vector_type(4)));
typedef __bf16 bf16x8 __attribute__((ext_vector_type(8)));
typedef float floatx4 __attribute__((ext_vector_type(4)));
typedef unsigned int u32;

#define N_NODES 4096
#define F_IN 128
#define NUM_HEADS 4
#define D_HID 64
#define F_OUT 256  // NUM_HEADS * D_HID
#define NEG_SLOPE 0.2f
#define LOG2E 1.4426950408889634f
#define NWORDS 128  // mask u32 words per adjacency row (4096/32)

// ---------------------------------------------------------------------------
// Kernel 0: adjacency -> TRANSPOSED packed bitmask maskT[jw][i].
// Reads: streaming 64 MiB (128-B chunks per thread, line-sequential).
// Writes: scattered u32 (2 MiB payload) -- latency-insensitive, ~2 us extra.
// Transposed layout makes the attn mask load COALESCED+BROADCAST:
// lanes 0..15 read 16 consecutive words, quads share the same line.
// ---------------------------------------------------------------------------
__global__ __launch_bounds__(256) void mask_kernel(
    const float* __restrict__ adj, u32* __restrict__ maskT)
{
    const int w = blockIdx.x * 256 + threadIdx.x;   // 0 .. 4096*128-1
    const float* src = adj + (size_t)w * 32;
    u32 bits = 0;
#pragma unroll
    for (int c = 0; c < 8; ++c) {
        const float4 v = *reinterpret_cast<const float4*>(src + c * 4);
        bits |= (u32)(v.x >= 0.5f) << (4 * c + 0);
        bits |= (u32)(v.y >= 0.5f) << (4 * c + 1);
        bits |= (u32)(v.z >= 0.5f) << (4 * c + 2);
        bits |= (u32)(v.w >= 0.5f) << (4 * c + 3);
    }
    const int row = w >> 7;          // node i
    const int jw  = w & 127;         // 32-col block
    maskT[(size_t)jw * N_NODES + row] = bits;
}

// ---------------------------------------------------------------------------
// Kernel 1: projections (f32 in; GB bf16 fragment-linear + el/er f32 out).
//   GB[h][j>>5][f>>4][lane=(f&15)+16*((j>>3)&3)][j&7]  (1 KB per B-fragment)
//   el/er PRE-SCALED by log2(e) so attn uses exp2 directly.
// 512 blocks x 384 threads; block handles 8 nodes.
// ---------------------------------------------------------------------------
__global__ __launch_bounds__(384) void proj_kernel(
    const float* __restrict__ hmat, const float* __restrict__ Wp,
    const float* __restrict__ Wa, const float* __restrict__ wattn,
    bf16_t* __restrict__ GB, float* __restrict__ el, float* __restrict__ er)
{
    const int t = threadIdx.x;
    const int j0 = blockIdx.x * 8;

    float acc[8] = {0.f, 0.f, 0.f, 0.f, 0.f, 0.f, 0.f, 0.f};

    const float* wptr;
    int stride;
    if (t < 256) { wptr = Wp + t;         stride = 256; }
    else         { wptr = Wa + (t - 256); stride = 128; }

    const float* hbase = hmat + (size_t)j0 * F_IN;

    for (int m = 0; m < F_IN; m += 4) {
        const float w0 = wptr[(size_t)(m + 0) * stride];
        const float w1 = wptr[(size_t)(m + 1) * stride];
        const float w2 = wptr[(size_t)(m + 2) * stride];
        const float w3 = wptr[(size_t)(m + 3) * stride];
#pragma unroll
        for (int jl = 0; jl < 8; ++jl) {
            const float4 hv = *reinterpret_cast<const float4*>(&hbase[jl * F_IN + m]);
            acc[jl] = fmaf(hv.w, w3, fmaf(hv.z, w2, fmaf(hv.y, w1, fmaf(hv.x, w0, acc[jl]))));
        }
    }

    if (t < 256) {
        const int h = t >> 6, f = t & 63;
        bf16x8 o;
#pragma unroll
        for (int q = 0; q < 8; ++q) o[q] = (bf16_t)acc[q];
        // j0 % 8 == 0: the 8 nodes fill one contiguous [j&7] run
        const size_t base = ((((size_t)h * 128 + (j0 >> 5)) * 4 + (f >> 4)) * 64
                             + (f & 15) + 16 * ((j0 >> 3) & 3)) * 8;
        *reinterpret_cast<bf16x8*>(&GB[base]) = o;
    } else {
        const int ta = t - 256;          // waves 4,5; 32-lane group per head
        const int ha = ta >> 5, k = ta & 31;
        const float wl = wattn[k] * LOG2E, wr = wattn[32 + k] * LOG2E;
#pragma unroll
        for (int jl = 0; jl < 8; ++jl) {
            float vl = acc[jl] * wl;
            float vr = acc[jl] * wr;
#pragma unroll
            for (int s = 16; s >= 1; s >>= 1) {
                vl += __shfl_xor(vl, s, 64);
                vr += __shfl_xor(vr, s, 64);
            }
            if (k == 0) {
                el[ha * N_NODES + j0 + jl] = vl;
                er[ha * N_NODES + j0 + jl] = vr;
            }
        }
    }
}

// ---------------------------------------------------------------------------
// Kernel 2: barrier-free fused attention. No LDS. 32-row waves, full
// depth-1 register prefetch (mask words, er, all 4 B-fragments).
// Grid (32 i-tiles of 128 rows, 8 jc, 4 heads) x 256 threads (4 waves)
//   = 1024 blocks = 4 blocks/CU = 16 waves/CU (4/SIMD).
// The 4 waves of a block share ONE head: per-step GB/er addresses are
// identical (i-independent) -> L1 dedup. Mask reads now hit the TRANSPOSED
// maskT: lanes 0..15 load 16 consecutive words (1 line, quad-broadcast)
// instead of a 32-line row gather -- the last uncoalesced load in the loop.
// Denominator = f32 VALU sum of P values.
// ---------------------------------------------------------------------------
__global__ __launch_bounds__(256, 4) void attn_kernel(
    const u32* __restrict__ maskT, const bf16_t* __restrict__ GB,
    const float* __restrict__ el, const float* __restrict__ er,
    float* __restrict__ numout, float* __restrict__ den_g,
    int ntiles)
{
    const int tid  = threadIdx.x;
    const int wave = tid >> 6;
    const int i0   = blockIdx.x * 128 + wave * 32;
    const int jc   = blockIdx.y;
    const int hh   = blockIdx.z;
    const int lane = tid & 63;
    const int m    = lane & 15;
    const int quad = lane >> 4;
    const int NS   = ntiles * 2;          // steps of 32 columns
    const int j32_0 = jc * NS;

    const float el_lo = el[hh * N_NODES + i0 + m];
    const float el_hi = el[hh * N_NODES + i0 + 16 + m];
    const u32*  mTp   = maskT + (size_t)j32_0 * N_NODES + i0 + m;  // +16 for hi
    const float* erp  = er + hh * N_NODES + j32_0 * 32 + quad * 8;
    const bf16_t* gb  = GB + (size_t)hh * (128 * 4 * 512)
                           + (size_t)j32_0 * 2048 + lane * 8;

    floatx4 accL0 = {0.f, 0.f, 0.f, 0.f};
    floatx4 accL1 = accL0, accL2 = accL0, accL3 = accL0;
    floatx4 accH0 = accL0, accH1 = accL0, accH2 = accL0, accH3 = accL0;
    float denL = 0.f, denH = 0.f;

    // prologue: full step-0 set in registers
    u32 mLc = mTp[0], mHc = mTp[16];
    float4 e0c = *reinterpret_cast<const float4*>(erp);
    float4 e1c = *reinterpret_cast<const float4*>(erp + 4);
    bf16x8 b0c = *reinterpret_cast<const bf16x8*>(gb);
    bf16x8 b1c = *reinterpret_cast<const bf16x8*>(gb + 512);
    bf16x8 b2c = *reinterpret_cast<const bf16x8*>(gb + 1024);
    bf16x8 b3c = *reinterpret_cast<const bf16x8*>(gb + 1536);

    for (int s = 0; s < NS; ++s) {
        const int d = (s + 1 < NS) ? 1 : 0;   // clamp on last step
        // ---- depth-1 prefetch of the ENTIRE next-step set ----
        const u32    mLn = mTp[(size_t)d * N_NODES];
        const u32    mHn = mTp[(size_t)d * N_NODES + 16];
        const float4 e0n = *reinterpret_cast<const float4*>(erp + d * 32);
        const float4 e1n = *reinterpret_cast<const float4*>(erp + d * 32 + 4);
        const bf16_t* gpn = gb + (size_t)d * 2048;
        const bf16x8 b0n = *reinterpret_cast<const bf16x8*>(gpn);
        const bf16x8 b1n = *reinterpret_cast<const bf16x8*>(gpn + 512);
        const bf16x8 b2n = *reinterpret_cast<const bf16x8*>(gpn + 1024);
        const bf16x8 b3n = *reinterpret_cast<const bf16x8*>(gpn + 1536);

        // ---- P fragments for 32 rows x 32 cols (this wave) ----
        const u32 byL = (mLc >> (quad * 8)) & 0xffu;
        const u32 byH = (mHc >> (quad * 8)) & 0xffu;
        const float ev[8] = {e0c.x, e0c.y, e0c.z, e0c.w, e1c.x, e1c.y, e1c.z, e1c.w};

        bf16x8 afL, afH;
        float dL = 0.f, dH = 0.f;
#pragma unroll
        for (int q = 0; q < 8; ++q) {
            float sL = el_lo + ev[q]; sL = fmaxf(sL, NEG_SLOPE * sL);
            float sH = el_hi + ev[q]; sH = fmaxf(sH, NEG_SLOPE * sH);
            const float pL = ((byL >> q) & 1u) ? __builtin_amdgcn_exp2f(sL) : 0.f;
            const float pH = ((byH >> q) & 1u) ? __builtin_amdgcn_exp2f(sH) : 0.f;
            dL += pL; dH += pH;
            afL[q] = (bf16_t)pL;
            afH[q] = (bf16_t)pH;
        }
        denL += dL; denH += dH;

        accL0 = __builtin_amdgcn_mfma_f32_16x16x32_bf16(afL, b0c, accL0, 0, 0, 0);
        accH0 = __builtin_amdgcn_mfma_f32_16x16x32_bf16(afH, b0c, accH0, 0, 0, 0);
        accL1 = __builtin_amdgcn_mfma_f32_16x16x32_bf16(afL, b1c, accL1, 0, 0, 0);
        accH1 = __builtin_amdgcn_mfma_f32_16x16x32_bf16(afH, b1c, accH1, 0, 0, 0);
        accL2 = __builtin_amdgcn_mfma_f32_16x16x32_bf16(afL, b2c, accL2, 0, 0, 0);
        accH2 = __builtin_amdgcn_mfma_f32_16x16x32_bf16(afH, b2c, accH2, 0, 0, 0);
        accL3 = __builtin_amdgcn_mfma_f32_16x16x32_bf16(afL, b3c, accL3, 0, 0, 0);
        accH3 = __builtin_amdgcn_mfma_f32_16x16x32_bf16(afH, b3c, accH3, 0, 0, 0);

        // rotate prefetched set in
        mLc = mLn; mHc = mHn; e0c = e0n; e1c = e1n;
        b0c = b0n; b1c = b1n; b2c = b2n; b3c = b3n;
        mTp += N_NODES;
        erp += 32;
        gb  += 2048;
    }

    // cross-quad den reduction (lanes {m,m+16,m+32,m+48} hold row partials)
    denL += __shfl_xor(denL, 16, 64);
    denL += __shfl_xor(denL, 32, 64);
    denH += __shfl_xor(denH, 16, 64);
    denH += __shfl_xor(denH, 32, 64);

    // epilogue: C/D row = quad*4 + r (lo) / +16 (hi), col = m
    float* nrow = numout + (size_t)jc * ((size_t)N_NODES * F_OUT);
    const int ibL = i0 + quad * 4;
    const int ibH = ibL + 16;
#pragma unroll
    for (int r = 0; r < 4; ++r) {
        float* dL = nrow + (size_t)(ibL + r) * F_OUT + hh * D_HID + m;
        dL[0]  = accL0[r];
        dL[16] = accL1[r];
        dL[32] = accL2[r];
        dL[48] = accL3[r];
        float* dH = nrow + (size_t)(ibH + r) * F_OUT + hh * D_HID + m;
        dH[0]  = accH0[r];
        dH[16] = accH1[r];
        dH[32] = accH2[r];
        dH[48] = accH3[r];
    }
    if (quad == 0) {
        den_g[((size_t)jc * N_NODES + i0 + m) * NUM_HEADS + hh] = denL;
        den_g[((size_t)jc * N_NODES + i0 + 16 + m) * NUM_HEADS + hh] = denH;
    }
}

// ---------------------------------------------------------------------------
// Kernel 3: sum chunk partials, divide, store f32 (float4-vectorized).
// ---------------------------------------------------------------------------
template<int NJC>
__global__ __launch_bounds__(256) void reduce_kernel(
    const float* __restrict__ num, const float* __restrict__ den,
    float* __restrict__ out)
{
    const int t4   = blockIdx.x * 256 + threadIdx.x;  // 0 .. N*F_OUT/4-1
    const int base = t4 * 4;
    const int i  = base >> 8;
    const int hh = (base & 255) >> 6;                 // same head for all 4 ch
    float4 n = {0.f, 0.f, 0.f, 0.f};
    float d = 0.f;
#pragma unroll
    for (int jc = 0; jc < NJC; ++jc) {
        const float4 v = *reinterpret_cast<const float4*>(
            num + (size_t)jc * ((size_t)N_NODES * F_OUT) + base);
        n.x += v.x; n.y += v.y; n.z += v.z; n.w += v.w;
        d += den[((size_t)jc * N_NODES + i) * NUM_HEADS + hh];
    }
    const float rd = 1.0f / d;
    float4 o = {n.x * rd, n.y * rd, n.z * rd, n.w * rd};
    *reinterpret_cast<float4*>(out + base) = o;
}

// ---------------------------------------------------------------------------
extern "C" void kernel_launch(void* const* d_in, const int* in_sizes, int n_in,
                              void* d_out, int out_size, void* d_ws, size_t ws_size,
                              hipStream_t stream)
{
    const float* hmat = (const float*)d_in[0];   // (4096, 128) f32
    const float* adj  = (const float*)d_in[1];   // (4096, 4096) f32
    const float* Wp   = (const float*)d_in[2];   // (128, 256) f32
    const float* Wa   = (const float*)d_in[3];   // (128, 128) f32
    const float* watt = (const float*)d_in[4];   // (64,) f32
    float* out = (float*)d_out;                  // (4096, 256) f32

    char* ws = (char*)d_ws;
    bf16_t* GB   = (bf16_t*)ws;                                  // 2 MiB
    float*  el   = (float*)(ws + (2ull << 20));                  // 64 KiB
    float*  er   = (float*)(ws + (2ull << 20) + (64ull << 10));  // 64 KiB
    u32*    mskT = (u32*)(ws + (2ull << 20) + (128ull << 10));   // 2 MiB
    const size_t baseoff = (4ull << 20) + (128ull << 10);

    const size_t num_bytes = (size_t)N_NODES * F_OUT * 4;          // 4 MiB per chunk
    const size_t den_bytes = (size_t)N_NODES * NUM_HEADS * 4;      // 64 KiB per chunk
    const int njc = (ws_size >= baseoff + 8 * (num_bytes + den_bytes)) ? 8
                  : (ws_size >= baseoff + 4 * (num_bytes + den_bytes)) ? 4 : 2;

    float* num = (float*)(ws + baseoff);
    float* den = (float*)(ws + baseoff + (size_t)njc * num_bytes);

    proj_kernel<<<512, 384, 0, stream>>>(hmat, Wp, Wa, watt, GB, el, er);
    mask_kernel<<<(N_NODES * NWORDS) / 256, 256, 0, stream>>>(adj, mskT);
    attn_kernel<<<dim3(32, njc, NUM_HEADS), 256, 0, stream>>>(
        mskT, GB, el, er, num, den, (N_NODES / njc) / 64);
    if (njc == 8)      reduce_kernel<8><<<(N_NODES * F_OUT) / 1024, 256, 0, stream>>>(num, den, out);
    else if (njc == 4) reduce_kernel<4><<<(N_NODES * F_OUT) / 1024, 256, 0, stream>>>(num, den, out);
    else               reduce_kernel<2><<<(N_NODES * F_OUT) / 1024, 256, 0, stream>>>(num, den, out);
}

// Round 8
// 161.708 us; speedup vs baseline: 1.0279x; 1.0279x over previous
//
#include <hip/hip_runtime.h>
#include <hip/hip_bf16.h>

typedef __bf16 bf16_t;
typedef __bf16 bf16x4 __attribute__((ext_vector_type(4)));
typedef __bf16 bf16x8 __attribute__((ext_vector_type(8)));
typedef float floatx2 __attribute__((ext_vector_type(2)));
typedef float floatx4 __attribute__((ext_vector_type(4)));
typedef unsigned int u32;

#define N_NODES 4096
#define F_IN 128
#define NUM_HEADS 4
#define D_HID 64
#define F_OUT 256  // NUM_HEADS * D_HID
#define NEG_SLOPE 0.2f
#define LOG2E 1.4426950408889634f
#define NWORDS 128        // mask u32 words per adjacency row (4096/32)
#define MASK_BLOCKS 1366  // ceil(4096*128 / 384)
#define PROJ_BLOCKS 512

// ---------------------------------------------------------------------------
// Kernel 0 (merged): mask blocks [0,1366) + proj blocks [1366,1878).
// mask: adjacency -> TRANSPOSED bitmask maskT[jw][i] (HBM-read-bound, 64 MiB).
// proj: h @ W (L2/compute-bound). Independent -> they overlap on the CUs,
// hiding proj almost entirely under mask's streaming time.
// ---------------------------------------------------------------------------
__global__ __launch_bounds__(384) void prep_kernel(
    const float* __restrict__ adj, u32* __restrict__ maskT,
    const float* __restrict__ hmat, const float* __restrict__ Wp,
    const float* __restrict__ Wa, const float* __restrict__ wattn,
    bf16_t* __restrict__ GB, float* __restrict__ el, float* __restrict__ er)
{
    if (blockIdx.x < MASK_BLOCKS) {
        // ---------------- mask part ----------------
        const int w = blockIdx.x * 384 + threadIdx.x;   // word index
        if (w < N_NODES * NWORDS) {
            const float* src = adj + (size_t)w * 32;
            u32 bits = 0;
#pragma unroll
            for (int c = 0; c < 8; ++c) {
                const float4 v = *reinterpret_cast<const float4*>(src + c * 4);
                bits |= (u32)(v.x >= 0.5f) << (4 * c + 0);
                bits |= (u32)(v.y >= 0.5f) << (4 * c + 1);
                bits |= (u32)(v.z >= 0.5f) << (4 * c + 2);
                bits |= (u32)(v.w >= 0.5f) << (4 * c + 3);
            }
            const int row = w >> 7;          // node i
            const int jw  = w & 127;         // 32-col block
            maskT[(size_t)jw * N_NODES + row] = bits;
        }
        return;
    }
    // ---------------- proj part ----------------
    // GB[h][j>>5][f>>4][lane=(f&15)+16*((j>>3)&3)][j&7]  (1 KB per B-fragment)
    // el/er PRE-SCALED by log2(e) so attn uses exp2 directly.
    const int t  = threadIdx.x;
    const int j0 = (blockIdx.x - MASK_BLOCKS) * 8;

    float acc[8] = {0.f, 0.f, 0.f, 0.f, 0.f, 0.f, 0.f, 0.f};

    const float* wptr;
    int stride;
    if (t < 256) { wptr = Wp + t;         stride = 256; }
    else         { wptr = Wa + (t - 256); stride = 128; }

    const float* hbase = hmat + (size_t)j0 * F_IN;

    for (int m = 0; m < F_IN; m += 4) {
        const float w0 = wptr[(size_t)(m + 0) * stride];
        const float w1 = wptr[(size_t)(m + 1) * stride];
        const float w2 = wptr[(size_t)(m + 2) * stride];
        const float w3 = wptr[(size_t)(m + 3) * stride];
#pragma unroll
        for (int jl = 0; jl < 8; ++jl) {
            const float4 hv = *reinterpret_cast<const float4*>(&hbase[jl * F_IN + m]);
            acc[jl] = fmaf(hv.w, w3, fmaf(hv.z, w2, fmaf(hv.y, w1, fmaf(hv.x, w0, acc[jl]))));
        }
    }

    if (t < 256) {
        const int h = t >> 6, f = t & 63;
        bf16x8 o;
#pragma unroll
        for (int q = 0; q < 8; ++q) o[q] = (bf16_t)acc[q];
        const size_t base = ((((size_t)h * 128 + (j0 >> 5)) * 4 + (f >> 4)) * 64
                             + (f & 15) + 16 * ((j0 >> 3) & 3)) * 8;
        *reinterpret_cast<bf16x8*>(&GB[base]) = o;
    } else {
        const int ta = t - 256;          // waves 4,5; 32-lane group per head
        const int ha = ta >> 5, k = ta & 31;
        const float wl = wattn[k] * LOG2E, wr = wattn[32 + k] * LOG2E;
#pragma unroll
        for (int jl = 0; jl < 8; ++jl) {
            float vl = acc[jl] * wl;
            float vr = acc[jl] * wr;
#pragma unroll
            for (int s = 16; s >= 1; s >>= 1) {
                vl += __shfl_xor(vl, s, 64);
                vr += __shfl_xor(vr, s, 64);
            }
            if (k == 0) {
                el[ha * N_NODES + j0 + jl] = vl;
                er[ha * N_NODES + j0 + jl] = vr;
            }
        }
    }
}

// ---------------------------------------------------------------------------
// Kernel 2: barrier-free fused attention. No LDS. 32-row waves, full
// depth-1 register prefetch. Grid (32, 8 jc, 4 heads) x 256 thr (4 waves,
// one head per block -> L1 dedup of GB/er). Packed-f32 (v_pk_*) P-compute;
// denominator on the idle MFMA pipe via ones-B fragment (frees ~16 VALU
// adds/step; C-layout row quad*4+r matches the numerator rows).
// ---------------------------------------------------------------------------
__global__ __launch_bounds__(256, 4) void attn_kernel(
    const u32* __restrict__ maskT, const bf16_t* __restrict__ GB,
    const float* __restrict__ el, const float* __restrict__ er,
    float* __restrict__ numout, float* __restrict__ den_g,
    int ntiles)
{
    const int tid  = threadIdx.x;
    const int wave = tid >> 6;
    const int i0   = blockIdx.x * 128 + wave * 32;
    const int jc   = blockIdx.y;
    const int hh   = blockIdx.z;
    const int lane = tid & 63;
    const int m    = lane & 15;
    const int quad = lane >> 4;
    const int NS   = ntiles * 2;          // steps of 32 columns
    const int j32_0 = jc * NS;

    const float el_lo = el[hh * N_NODES + i0 + m];
    const float el_hi = el[hh * N_NODES + i0 + 16 + m];
    const u32*  mTp   = maskT + (size_t)j32_0 * N_NODES + i0 + m;  // +16 for hi
    const float* erp  = er + hh * N_NODES + j32_0 * 32 + quad * 8;
    const bf16_t* gb  = GB + (size_t)hh * (128 * 4 * 512)
                           + (size_t)j32_0 * 2048 + lane * 8;

    floatx4 accL0 = {0.f, 0.f, 0.f, 0.f};
    floatx4 accL1 = accL0, accL2 = accL0, accL3 = accL0, accdL = accL0;
    floatx4 accH0 = accL0, accH1 = accL0, accH2 = accL0, accH3 = accL0, accdH = accL0;
    bf16x8 ones;
#pragma unroll
    for (int q = 0; q < 8; ++q) ones[q] = (bf16_t)1.0f;

    // prologue: full step-0 set in registers
    u32 mLc = mTp[0], mHc = mTp[16];
    float4 e0c = *reinterpret_cast<const float4*>(erp);
    float4 e1c = *reinterpret_cast<const float4*>(erp + 4);
    bf16x8 b0c = *reinterpret_cast<const bf16x8*>(gb);
    bf16x8 b1c = *reinterpret_cast<const bf16x8*>(gb + 512);
    bf16x8 b2c = *reinterpret_cast<const bf16x8*>(gb + 1024);
    bf16x8 b3c = *reinterpret_cast<const bf16x8*>(gb + 1536);

    for (int s = 0; s < NS; ++s) {
        const int d = (s + 1 < NS) ? 1 : 0;   // clamp on last step
        // ---- depth-1 prefetch of the ENTIRE next-step set ----
        const u32    mLn = mTp[(size_t)d * N_NODES];
        const u32    mHn = mTp[(size_t)d * N_NODES + 16];
        const float4 e0n = *reinterpret_cast<const float4*>(erp + d * 32);
        const float4 e1n = *reinterpret_cast<const float4*>(erp + d * 32 + 4);
        const bf16_t* gpn = gb + (size_t)d * 2048;
        const bf16x8 b0n = *reinterpret_cast<const bf16x8*>(gpn);
        const bf16x8 b1n = *reinterpret_cast<const bf16x8*>(gpn + 512);
        const bf16x8 b2n = *reinterpret_cast<const bf16x8*>(gpn + 1024);
        const bf16x8 b3n = *reinterpret_cast<const bf16x8*>(gpn + 1536);

        // ---- P fragments: packed-f32 leaky-relu, masked exp2 ----
        const u32 byL = (mLc >> (quad * 8)) & 0xffu;
        const u32 byH = (mHc >> (quad * 8)) & 0xffu;
        const floatx2 evp[4] = {{e0c.x, e0c.y}, {e0c.z, e0c.w},
                                {e1c.x, e1c.y}, {e1c.z, e1c.w}};
        const floatx2 eL2 = {el_lo, el_lo};
        const floatx2 eH2 = {el_hi, el_hi};

        bf16x8 afL, afH;
#pragma unroll
        for (int qp = 0; qp < 4; ++qp) {
            floatx2 sL = eL2 + evp[qp];                       // v_pk_add_f32
            floatx2 sH = eH2 + evp[qp];
            sL = __builtin_elementwise_max(sL, sL * NEG_SLOPE);  // v_pk_mul/max
            sH = __builtin_elementwise_max(sH, sH * NEG_SLOPE);
            const float pL0 = ((byL >> (2 * qp))     & 1u) ? __builtin_amdgcn_exp2f(sL.x) : 0.f;
            const float pL1 = ((byL >> (2 * qp + 1)) & 1u) ? __builtin_amdgcn_exp2f(sL.y) : 0.f;
            const float pH0 = ((byH >> (2 * qp))     & 1u) ? __builtin_amdgcn_exp2f(sH.x) : 0.f;
            const float pH1 = ((byH >> (2 * qp + 1)) & 1u) ? __builtin_amdgcn_exp2f(sH.y) : 0.f;
            afL[2 * qp]     = (bf16_t)pL0;
            afL[2 * qp + 1] = (bf16_t)pL1;
            afH[2 * qp]     = (bf16_t)pH0;
            afH[2 * qp + 1] = (bf16_t)pH1;
        }

        // denominator on the (idle) MFMA pipe
        accdL = __builtin_amdgcn_mfma_f32_16x16x32_bf16(afL, ones, accdL, 0, 0, 0);
        accdH = __builtin_amdgcn_mfma_f32_16x16x32_bf16(afH, ones, accdH, 0, 0, 0);

        accL0 = __builtin_amdgcn_mfma_f32_16x16x32_bf16(afL, b0c, accL0, 0, 0, 0);
        accH0 = __builtin_amdgcn_mfma_f32_16x16x32_bf16(afH, b0c, accH0, 0, 0, 0);
        accL1 = __builtin_amdgcn_mfma_f32_16x16x32_bf16(afL, b1c, accL1, 0, 0, 0);
        accH1 = __builtin_amdgcn_mfma_f32_16x16x32_bf16(afH, b1c, accH1, 0, 0, 0);
        accL2 = __builtin_amdgcn_mfma_f32_16x16x32_bf16(afL, b2c, accL2, 0, 0, 0);
        accH2 = __builtin_amdgcn_mfma_f32_16x16x32_bf16(afH, b2c, accH2, 0, 0, 0);
        accL3 = __builtin_amdgcn_mfma_f32_16x16x32_bf16(afL, b3c, accL3, 0, 0, 0);
        accH3 = __builtin_amdgcn_mfma_f32_16x16x32_bf16(afH, b3c, accH3, 0, 0, 0);

        // rotate prefetched set in
        mLc = mLn; mHc = mHn; e0c = e0n; e1c = e1n;
        b0c = b0n; b1c = b1n; b2c = b2n; b3c = b3n;
        mTp += N_NODES;
        erp += 32;
        gb  += 2048;
    }

    // epilogue: C/D row = quad*4 + r (lo) / +16 (hi), col = m.
    // accd[r] = rowsum(P[quad*4+r]) replicated across m -> store at m==0.
    float* nrow = numout + (size_t)jc * ((size_t)N_NODES * F_OUT);
    const int ibL = i0 + quad * 4;
    const int ibH = ibL + 16;
#pragma unroll
    for (int r = 0; r < 4; ++r) {
        float* dL = nrow + (size_t)(ibL + r) * F_OUT + hh * D_HID + m;
        dL[0]  = accL0[r];
        dL[16] = accL1[r];
        dL[32] = accL2[r];
        dL[48] = accL3[r];
        float* dH = nrow + (size_t)(ibH + r) * F_OUT + hh * D_HID + m;
        dH[0]  = accH0[r];
        dH[16] = accH1[r];
        dH[32] = accH2[r];
        dH[48] = accH3[r];
    }
    if (m == 0) {
#pragma unroll
        for (int r = 0; r < 4; ++r) {
            den_g[((size_t)jc * N_NODES + ibL + r) * NUM_HEADS + hh] = accdL[r];
            den_g[((size_t)jc * N_NODES + ibH + r) * NUM_HEADS + hh] = accdH[r];
        }
    }
}

// ---------------------------------------------------------------------------
// Kernel 3: sum chunk partials, divide, store f32 (float4-vectorized).
// ---------------------------------------------------------------------------
template<int NJC>
__global__ __launch_bounds__(256) void reduce_kernel(
    const float* __restrict__ num, const float* __restrict__ den,
    float* __restrict__ out)
{
    const int t4   = blockIdx.x * 256 + threadIdx.x;  // 0 .. N*F_OUT/4-1
    const int base = t4 * 4;
    const int i  = base >> 8;
    const int hh = (base & 255) >> 6;                 // same head for all 4 ch
    float4 n = {0.f, 0.f, 0.f, 0.f};
    float d = 0.f;
#pragma unroll
    for (int jc = 0; jc < NJC; ++jc) {
        const float4 v = *reinterpret_cast<const float4*>(
            num + (size_t)jc * ((size_t)N_NODES * F_OUT) + base);
        n.x += v.x; n.y += v.y; n.z += v.z; n.w += v.w;
        d += den[((size_t)jc * N_NODES + i) * NUM_HEADS + hh];
    }
    const float rd = 1.0f / d;
    float4 o = {n.x * rd, n.y * rd, n.z * rd, n.w * rd};
    *reinterpret_cast<float4*>(out + base) = o;
}

// ---------------------------------------------------------------------------
extern "C" void kernel_launch(void* const* d_in, const int* in_sizes, int n_in,
                              void* d_out, int out_size, void* d_ws, size_t ws_size,
                              hipStream_t stream)
{
    const float* hmat = (const float*)d_in[0];   // (4096, 128) f32
    const float* adj  = (const float*)d_in[1];   // (4096, 4096) f32
    const float* Wp   = (const float*)d_in[2];   // (128, 256) f32
    const float* Wa   = (const float*)d_in[3];   // (128, 128) f32
    const float* watt = (const float*)d_in[4];   // (64,) f32
    float* out = (float*)d_out;                  // (4096, 256) f32

    char* ws = (char*)d_ws;
    bf16_t* GB   = (bf16_t*)ws;                                  // 2 MiB
    float*  el   = (float*)(ws + (2ull << 20));                  // 64 KiB
    float*  er   = (float*)(ws + (2ull << 20) + (64ull << 10));  // 64 KiB
    u32*    mskT = (u32*)(ws + (2ull << 20) + (128ull << 10));   // 2 MiB
    const size_t baseoff = (4ull << 20) + (128ull << 10);

    const size_t num_bytes = (size_t)N_NODES * F_OUT * 4;          // 4 MiB per chunk
    const size_t den_bytes = (size_t)N_NODES * NUM_HEADS * 4;      // 64 KiB per chunk
    const int njc = (ws_size >= baseoff + 8 * (num_bytes + den_bytes)) ? 8
                  : (ws_size >= baseoff + 4 * (num_bytes + den_bytes)) ? 4 : 2;

    float* num = (float*)(ws + baseoff);
    float* den = (float*)(ws + baseoff + (size_t)njc * num_bytes);

    prep_kernel<<<MASK_BLOCKS + PROJ_BLOCKS, 384, 0, stream>>>(
        adj, mskT, hmat, Wp, Wa, watt, GB, el, er);
    attn_kernel<<<dim3(32, njc, NUM_HEADS), 256, 0, stream>>>(
        mskT, GB, el, er, num, den, (N_NODES / njc) / 64);
    if (njc == 8)      reduce_kernel<8><<<(N_NODES * F_OUT) / 1024, 256, 0, stream>>>(num, den, out);
    else if (njc == 4) reduce_kernel<4><<<(N_NODES * F_OUT) / 1024, 256, 0, stream>>>(num, den, out);
    else               reduce_kernel<2><<<(N_NODES * F_OUT) / 1024, 256, 0, stream>>>(num, den, out);
}